// Round 7
// baseline (77.127 us; speedup 1.0000x reference)
//
#include <hip/hip_runtime.h>
#include <math.h>

#define BB 4
#define LL 512
#define NROW (BB*LL)      // 2048
#define DD 128
#define DEG 511.0f
#define SCALE 0.08838834764831845f   // 1/sqrt(128)

typedef short bf16x8 __attribute__((ext_vector_type(8)));
typedef float f32x4 __attribute__((ext_vector_type(4)));

static __device__ __forceinline__ ushort f2bf(float f) {
  unsigned u = __float_as_uint(f);
  u = (u + 0x7fffu + ((u >> 16) & 1u)) >> 16;   // RNE
  return (ushort)u;
}

// =============== K1: fused front+adjacency (R6-verbatim) ===============
__global__ __launch_bounds__(256) void k_fused(
    const float* __restrict__ inputs, const float* __restrict__ coords,
    const float* __restrict__ cc,
    const float* __restrict__ Wc, const float* __restrict__ bc,
    const float* __restrict__ Wcc, const float* __restrict__ bcc,
    const float* __restrict__ Wa, const float* __restrict__ ba,
    const float* __restrict__ Wb, const float* __restrict__ bb,
    float* __restrict__ diffpart, float* __restrict__ minval, int* __restrict__ minidx) {
  __shared__ ushort E1[64][136], E2[64][136];
  __shared__ ushort aT[64][136], acT[64][136], bT[64][136], bcT[64][136];
  __shared__ float bcS[128], bccS[128], biasS[128], headIn[12];
  __shared__ float red[256];
  __shared__ __align__(16) char uni[34816];   // union: fin1/fin2 (6 KB) | WT (34 KB)
  float (*fin1)[12] = (float(*)[12])uni;
  float (*fin2)[12] = (float(*)[12])(uni + 3072);
  ushort (*WT)[136] = (ushort(*)[136])uni;

  int t = threadIdx.x;
  int ix = blockIdx.x, jy = blockIdx.y, b = blockIdx.z;
  int i0 = b*LL + ix*64, j0 = b*LL + jy*64;
  int lane = t & 63, wave = t >> 6;
  int d = t & 127;

  if (t < 128) { bcS[t] = bc[t]; bccS[t] = bcc[t]; }
  if (t < 12)  headIn[t] = (t < 10) ? inputs[(size_t)(b*LL)*10 + t] : 0.f;
  float wcR[12], wccR[12];
#pragma unroll
  for (int k = 0; k < 12; ++k) { wcR[k] = Wc[k*DD + d]; wccR[k] = Wcc[k*DD + d]; }
  __syncthreads();

  for (int side = 0; side < 2; ++side) {
    int rows0 = side ? j0 : i0;
    const float* W    = side ? Wb : Wa;
    const float* bias = side ? bb : ba;
    // S1: features
    for (int idx = t; idx < 768; idx += 256) {
      int r = idx / 12, k = idx - r*12;
      int grow = rows0 + r;
      float f1, f2;
      if (k < 10) { float v = inputs[(size_t)grow*10 + k]; f1 = v; f2 = v - headIn[k]; }
      else        { f1 = coords[(size_t)grow*2 + (k-10)]; f2 = cc[(size_t)grow*2 + (k-10)]; }
      fin1[r][k] = f1; fin2[r][k] = f2;
    }
    __syncthreads();
    // S2: embeddings
    {
      int r0 = t >> 7;
      for (int it = 0; it < 32; ++it) {
        int r = r0 + it*2;
        float e1 = bcS[d], e2 = bccS[d];
#pragma unroll
        for (int k = 0; k < 12; ++k) { e1 += fin1[r][k]*wcR[k]; e2 += fin2[r][k]*wccR[k]; }
        E1[r][d] = f2bf(e1); E2[r][d] = f2bf(e2);
      }
    }
    __syncthreads();   // fin dead -> WT may overwrite
    // S3: stage transposed bf16 weight + bias
    for (int idx = t; idx < 16384; idx += 256) {
      int kk = idx >> 7, dd = idx & 127;
      WT[dd][kk] = f2bf(W[idx]);
    }
    if (t < 128) biasS[t] = bias[t];
    __syncthreads();
    // S4: projection MFMA: out = E @ W + bias (16 rows per wave)
    {
      ushort (*o1)[136] = side ? bT : aT;
      ushort (*o2)[136] = side ? bcT : acT;
      int rloc = lane & 15, koff = (lane >> 4)*8;
      int rbase = wave*16;
      for (int ct = 0; ct < 8; ++ct) {
        f32x4 p1 = {0.f,0.f,0.f,0.f}, p2 = {0.f,0.f,0.f,0.f};
#pragma unroll
        for (int ks = 0; ks < 4; ++ks) {
          bf16x8 ef1 = *(const bf16x8*)&E1[rbase + rloc][ks*32 + koff];
          bf16x8 ef2 = *(const bf16x8*)&E2[rbase + rloc][ks*32 + koff];
          bf16x8 wf  = *(const bf16x8*)&WT[ct*16 + rloc][ks*32 + koff];
          p1 = __builtin_amdgcn_mfma_f32_16x16x32_bf16(ef1, wf, p1, 0,0,0);
          p2 = __builtin_amdgcn_mfma_f32_16x16x32_bf16(ef2, wf, p2, 0,0,0);
        }
        int col = ct*16 + rloc;
        float bv = biasS[col];
#pragma unroll
        for (int r = 0; r < 4; ++r) {
          int row = rbase + (lane>>4)*4 + r;
          o1[row][col] = f2bf(p1[r] + bv);
          o2[row][col] = f2bf(p2[r] + bv);
        }
      }
    }
    __syncthreads();
  }

  // adjacency
  int rloc = lane & 15, koff = (lane >> 4)*8;
  bf16x8 av[4], acv[4];
#pragma unroll
  for (int ks = 0; ks < 4; ++ks) {
    av[ks]  = *(const bf16x8*)&aT[wave*16 + rloc][ks*32 + koff];
    acv[ks] = *(const bf16x8*)&acT[wave*16 + rloc][ks*32 + koff];
  }
  f32x4 zf = {0.f,0.f,0.f,0.f};
  f32x4 acc[4], accc[4];
#pragma unroll
  for (int jt = 0; jt < 4; ++jt) { acc[jt] = zf; accc[jt] = zf; }
#pragma unroll
  for (int ks = 0; ks < 4; ++ks) {
#pragma unroll
    for (int jt = 0; jt < 4; ++jt) {
      bf16x8 bv  = *(const bf16x8*)&bT[jt*16 + rloc][ks*32 + koff];
      bf16x8 bcv = *(const bf16x8*)&bcT[jt*16 + rloc][ks*32 + koff];
      acc[jt]  = __builtin_amdgcn_mfma_f32_16x16x32_bf16(av[ks],  bv,  acc[jt],  0,0,0);
      accc[jt] = __builtin_amdgcn_mfma_f32_16x16x32_bf16(acv[ks], bcv, accc[jt], 0,0,0);
    }
  }
  int g = lane >> 4, c = lane & 15;
  float sq = 0.f;
#pragma unroll
  for (int r = 0; r < 4; ++r) {
    float mn = INFINITY; int mi = -1;
#pragma unroll
    for (int jt = 0; jt < 4; ++jt) {
      float v  = acc[jt][r]  * SCALE;
      float vc = accc[jt][r] * SCALE;
      float dd = v - vc;
      sq += dd*dd;
      int j = j0 + jt*16 + c;
      if (v < mn || (v == mn && j > mi)) { mn = v; mi = j; }
    }
#pragma unroll
    for (int msk = 1; msk < 16; msk <<= 1) {
      float ov = __shfl_xor(mn, msk);
      int   oi = __shfl_xor(mi, msk);
      if (ov < mn || (ov == mn && oi > mi)) { mn = ov; mi = oi; }
    }
    if (c == 0) {
      int gi = i0 + wave*16 + g*4 + r;
      minval[gi*8 + jy] = mn;
      minidx[gi*8 + jy] = mi;
    }
  }
  red[t] = sq;
  __syncthreads();
  for (int off = 128; off > 0; off >>= 1) {
    if (t < off) red[t] += red[t+off];
    __syncthreads();
  }
  if (t == 0) diffpart[(b*8 + jy)*8 + ix] = red[0];
}

// =============== K2: per-batch tail — coalesced P/Q stores via swapped MFMA ==============
__global__ __launch_bounds__(1024) void k_tail2(
    const float* __restrict__ inputs, const float* __restrict__ coords,
    const float* __restrict__ cc,
    const float* __restrict__ Wc, const float* __restrict__ bc,
    const float* __restrict__ Wcc, const float* __restrict__ bcc,
    const float* __restrict__ W1l, const float* __restrict__ b1l,
    const float* __restrict__ W1r,
    const float* __restrict__ minval, const int* __restrict__ minidx,
    const float* __restrict__ diffpart, const float* __restrict__ targets,
    const float* __restrict__ W2l, const float* __restrict__ b2l,
    const float* __restrict__ W2r,
    float* __restrict__ Pg, float* __restrict__ Qg, float* __restrict__ out) {
  __shared__ ushort W1lT[128][136], W1rT[128][136];
  __shared__ ushort xT[128][136];
  __shared__ float finC1[128][12], finC2[128][12];
  __shared__ float dbcS[128], headIn[12];
  __shared__ float xs[128], sbv[128];
  __shared__ float part[8][128];
  __shared__ int aminL[LL];
  __shared__ float dred[256];

  int b = blockIdx.x, t = threadIdx.x;
  int d = t & 127, h = t >> 7;      // h: 0..7
  int lane = t & 63;

  // T0: stage transposed bf16 W1l/W1r, dbc, head
  for (int idx = t; idx < 16384; idx += 1024) {
    int kk = idx >> 7, dd = idx & 127;
    W1lT[dd][kk] = f2bf(W1l[idx]);
    W1rT[dd][kk] = f2bf(W1r[idx]);
  }
  if (t < 128) dbcS[t] = bc[t] - bcc[t];
  if (t < 12)  headIn[t] = (t < 10) ? inputs[(size_t)(b*LL)*10 + t] : 0.f;
  float wcR[12], wccR[12];
#pragma unroll
  for (int k = 0; k < 12; ++k) { wcR[k] = Wc[k*DD + d]; wccR[k] = Wcc[k*DD + d]; }

  // T1: chunks of 128 rows: x compute + P,Q projection (swapped operands)
  float csx = 0.f;
  for (int cch = 0; cch < 4; ++cch) {
    int rows0 = b*LL + cch*128;
    __syncthreads();
    for (int idx = t; idx < 1536; idx += 1024) {
      int r = idx / 12, k = idx - r*12;
      int grow = rows0 + r;
      float f1, f2;
      if (k < 10) { float v = inputs[(size_t)grow*10 + k]; f1 = v; f2 = v - headIn[k]; }
      else        { f1 = coords[(size_t)grow*2 + (k-10)]; f2 = cc[(size_t)grow*2 + (k-10)]; }
      finC1[r][k] = f1; finC2[r][k] = f2;
    }
    __syncthreads();
    for (int rr = 0; rr < 16; ++rr) {
      int r = h*16 + rr;
      float xv = dbcS[d];
#pragma unroll
      for (int k = 0; k < 12; ++k) xv += finC1[r][k]*wcR[k] - finC2[r][k]*wccR[k];
      xT[r][d] = f2bf(xv);
      csx += xv;
    }
    __syncthreads();
    // P,Q via MFMA, swapped: C[wcol][xrow] -> each lane holds float4 of consecutive wcols
    {
      int w = t >> 6;
      int rg = w & 7, mat = w >> 3;
      int rloc = lane & 15, koff = (lane >> 4)*8;
      const ushort (*WTp)[136] = mat ? W1rT : W1lT;
      float* dst = mat ? Qg : Pg;
      int xrow = rows0 + rg*16 + rloc;               // this lane's output row
      for (int ct = 0; ct < 8; ++ct) {
        f32x4 p = {0.f,0.f,0.f,0.f};
#pragma unroll
        for (int ks = 0; ks < 4; ++ks) {
          bf16x8 wf = *(const bf16x8*)&WTp[ct*16 + rloc][ks*32 + koff];
          bf16x8 af = *(const bf16x8*)&xT[rg*16 + rloc][ks*32 + koff];
          p = __builtin_amdgcn_mfma_f32_16x16x32_bf16(wf, af, p, 0,0,0);
        }
        int wcol0 = ct*16 + (lane>>4)*4;
        *(float4*)&dst[(size_t)xrow*DD + wcol0] = make_float4(p[0], p[1], p[2], p[3]);
      }
    }
  }
  __syncthreads();

  // T2: colsum combine + T3: argmin finalize
  part[h][d] = csx;
  if (t < LL) {
    int row = b*LL + t;
    float mv = minval[row*8]; int mi = minidx[row*8];
#pragma unroll
    for (int ch = 1; ch < 8; ++ch) {
      float v = minval[row*8 + ch]; int i2 = minidx[row*8 + ch];
      if (v < mv || (v == mv && i2 > mi)) { mv = v; mi = i2; }
    }
    aminL[t] = mi;
  }
  __syncthreads();
  if (h == 0) {
    float v = 0.f;
#pragma unroll
    for (int q = 0; q < 8; ++q) v += part[q][d];
    xs[d] = v;
  }
  __syncthreads();
  // T4: sb = colsum(x) @ W1l
  {
    float acc = 0.f;
#pragma unroll
    for (int k = h*16; k < h*16 + 16; ++k) acc += xs[k] * W1l[k*DD + d];
    part[h][d] = acc;
  }
  __syncthreads();
  if (h == 0) {
    float v = 0.f;
#pragma unroll
    for (int q = 0; q < 8; ++q) v += part[q][d];
    sbv[d] = v;
  }
  __syncthreads();
  float base = sbv[d] * (1.0f/DEG) + b1l[d];
  // T6: stream h1, accumulate colsum(h1)
  float csum = 0.f;
  int l0 = h*64;
#pragma unroll 4
  for (int r = 0; r < 64; ++r) {
    int li = l0 + r;
    int am = aminL[li];
    float v = base - Pg[(size_t)am*DD + d] * (1.0f/DEG) + Qg[(size_t)(b*LL + li)*DD + d];
    csum += fmaxf(v, 0.f);
  }
  part[h][d] = csum;
  __syncthreads();
  if (h == 0) {
    float colsum = 0.f;
#pragma unroll
    for (int q = 0; q < 8; ++q) colsum += part[q][d];
    int amh = aminL[0];
    int am2 = aminL[amh - b*LL];
    float h1head = fmaxf(base - Pg[(size_t)amh*DD + d]*(1.0f/DEG) + Qg[(size_t)(b*LL)*DD + d], 0.f);
    float h1am   = fmaxf(base - Pg[(size_t)am2*DD + d]*(1.0f/DEG) + Qg[(size_t)amh*DD + d], 0.f);
    float agg = (colsum - h1am) * (1.0f/DEG);
    part[0][d] = agg * W2l[d] + h1head * W2r[d];
  }
  __syncthreads();
  if (t < 64) {
    float v = part[0][t] + part[0][t + 64];
#pragma unroll
    for (int msk = 32; msk > 0; msk >>= 1) v += __shfl_down(v, msk);
    if (t == 0) out[b] = v + b2l[0];
  }
  // T8: diff + targets (block 0)
  if (b == 0) {
    if (t < 256) dred[t] = diffpart[t];
    __syncthreads();
    for (int off = 128; off > 0; off >>= 1) {
      if (t < off) dred[t] += dred[t+off];
      __syncthreads();
    }
    if (t == 0) out[4] = dred[0] / (float)((float)BB*LL*LL);
    if (t < 4) out[5+t] = targets[t*LL];
  }
}

extern "C" void kernel_launch(void* const* d_in, const int* in_sizes, int n_in,
                              void* d_out, int out_size, void* d_ws, size_t ws_size,
                              hipStream_t stream) {
  const float* inputs  = (const float*)d_in[0];
  const float* coords  = (const float*)d_in[1];
  const float* targets = (const float*)d_in[2];
  const float* cc      = (const float*)d_in[3];
  const float* Wc  = (const float*)d_in[5];
  const float* bc  = (const float*)d_in[6];
  const float* Wcc = (const float*)d_in[7];
  const float* bcc = (const float*)d_in[8];
  const float* Wa  = (const float*)d_in[9];
  const float* ba  = (const float*)d_in[10];
  const float* Wb  = (const float*)d_in[11];
  const float* bb  = (const float*)d_in[12];
  const float* W1l = (const float*)d_in[13];
  const float* b1l = (const float*)d_in[14];
  const float* W1r = (const float*)d_in[15];
  const float* W2l = (const float*)d_in[16];
  const float* b2l = (const float*)d_in[17];
  const float* W2r = (const float*)d_in[18];
  float* out = (float*)d_out;

  float* ws = (float*)d_ws;
  float* Pg = ws;                                  // NROW*DD
  float* Qg = ws + (size_t)NROW*DD;                // NROW*DD
  float* diffpart = ws + (size_t)2*NROW*DD;        // 256
  float* minval   = diffpart + 256;                // NROW*8
  int*   minidx   = (int*)(minval + (size_t)NROW*8);

  k_fused<<<dim3(8, 8, 4), 256, 0, stream>>>(inputs, coords, cc, Wc, bc, Wcc, bcc,
                                             Wa, ba, Wb, bb, diffpart, minval, minidx);
  k_tail2<<<4, 1024, 0, stream>>>(inputs, coords, cc, Wc, bc, Wcc, bcc,
                                  W1l, b1l, W1r, minval, minidx, diffpart, targets,
                                  W2l, b2l, W2r, Pg, Qg, out);
}

// Round 8
// 71.178 us; speedup vs baseline: 1.0836x; 1.0836x over previous
//
#include <hip/hip_runtime.h>
#include <math.h>

#define BB 4
#define LL 512
#define NROW (BB*LL)      // 2048
#define DD 128
#define DEG 511.0f
#define SCALE 0.08838834764831845f   // 1/sqrt(128)

typedef short bf16x8 __attribute__((ext_vector_type(8)));
typedef float f32x4 __attribute__((ext_vector_type(4)));

static __device__ __forceinline__ ushort f2bf(float f) {
  unsigned u = __float_as_uint(f);
  u = (u + 0x7fffu + ((u >> 16) & 1u)) >> 16;   // RNE
  return (ushort)u;
}
static __device__ __forceinline__ float bf2f(ushort u) {
  unsigned v = ((unsigned)u) << 16;
  return __uint_as_float(v);
}

// =============== K1: fused front+adjacency, MFMA embeddings ===============
// grid (8,8,4), 256 thr, ~156 KB LDS, 1 block/CU.
__global__ __launch_bounds__(256) void k_fused(
    const float* __restrict__ inputs, const float* __restrict__ coords,
    const float* __restrict__ cc,
    const float* __restrict__ Wc, const float* __restrict__ bc,
    const float* __restrict__ Wcc, const float* __restrict__ bcc,
    const float* __restrict__ Wa, const float* __restrict__ ba,
    const float* __restrict__ Wb, const float* __restrict__ bb,
    float* __restrict__ diffpart, float* __restrict__ minval, int* __restrict__ minidx) {
  __shared__ ushort E1[64][136], E2[64][136];
  __shared__ ushort aT[64][136], acT[64][136], bT[64][136], bcT[64][136];
  __shared__ ushort WcT[128][36], WccT[128][36];    // [d][k], k 0..11 used, 12..31 zero
  __shared__ float bcS[128], bccS[128], biasS[128], headIn[12];
  __shared__ float red[256];
  __shared__ __align__(16) char uni[34816];   // WT[128][136] ∪ fin1B/fin2B[64][32]
  ushort (*WT)[136] = (ushort(*)[136])uni;
  ushort (*fin1B)[32] = (ushort(*)[32])uni;
  ushort (*fin2B)[32] = (ushort(*)[32])(uni + 4096);

  int t = threadIdx.x;
  int ix = blockIdx.x, jy = blockIdx.y, b = blockIdx.z;
  int i0 = b*LL + ix*64, j0 = b*LL + jy*64;
  int lane = t & 63, wave = t >> 6;
  int rloc = lane & 15, koff = (lane >> 4) * 8;

  // P0: stage WcT/WccT (zero-padded K), biases, head features
  for (int idx = t; idx < 4096; idx += 256) {
    int d2 = idx >> 5, k = idx & 31;
    WcT[d2][k]  = (k < 12) ? f2bf(Wc[k*DD + d2])  : 0;
    WccT[d2][k] = (k < 12) ? f2bf(Wcc[k*DD + d2]) : 0;
  }
  if (t < 128) { bcS[t] = bc[t]; bccS[t] = bcc[t]; }
  if (t < 12)  headIn[t] = (t < 10) ? inputs[(size_t)(b*LL)*10 + t] : 0.f;
  __syncthreads();

  for (int side = 0; side < 2; ++side) {
    int rows0 = side ? j0 : i0;
    const float* W    = side ? Wb : Wa;
    const float* bias = side ? bb : ba;
    // S1: stage features as bf16 A-tiles [64][32]
    for (int idx = t; idx < 2048; idx += 256) {
      int r = idx >> 5, k = idx & 31;
      int grow = rows0 + r;
      float f1 = 0.f, f2 = 0.f;
      if (k < 10)      { f1 = inputs[(size_t)grow*10 + k]; f2 = f1 - headIn[k]; }
      else if (k < 12) { f1 = coords[(size_t)grow*2 + (k-10)]; f2 = cc[(size_t)grow*2 + (k-10)]; }
      fin1B[r][k] = f2bf(f1);
      fin2B[r][k] = f2bf(f2);
    }
    __syncthreads();
    // S2: E1/E2 via MFMA (rowgroup = wave)
    {
      int rg = wave;
      bf16x8 af1 = *(const bf16x8*)&fin1B[rg*16 + rloc][koff];
      bf16x8 af2 = *(const bf16x8*)&fin2B[rg*16 + rloc][koff];
      for (int cg = 0; cg < 8; ++cg) {
        bf16x8 wf1 = *(const bf16x8*)&WcT[cg*16 + rloc][koff];
        bf16x8 wf2 = *(const bf16x8*)&WccT[cg*16 + rloc][koff];
        float bv1 = bcS[cg*16 + rloc], bv2 = bccS[cg*16 + rloc];
        f32x4 p1 = {bv1, bv1, bv1, bv1};
        f32x4 p2 = {bv2, bv2, bv2, bv2};
        p1 = __builtin_amdgcn_mfma_f32_16x16x32_bf16(af1, wf1, p1, 0,0,0);
        p2 = __builtin_amdgcn_mfma_f32_16x16x32_bf16(af2, wf2, p2, 0,0,0);
        int col = cg*16 + rloc;
#pragma unroll
        for (int r = 0; r < 4; ++r) {
          int row = rg*16 + (lane>>4)*4 + r;
          E1[row][col] = f2bf(p1[r]);
          E2[row][col] = f2bf(p2[r]);
        }
      }
    }
    __syncthreads();   // finB dead -> WT may overwrite
    // S3: stage transposed bf16 weight + bias
    for (int idx = t; idx < 16384; idx += 256) {
      int kk = idx >> 7, dd = idx & 127;
      WT[dd][kk] = f2bf(W[idx]);
    }
    if (t < 128) biasS[t] = bias[t];
    __syncthreads();
    // S4: projection MFMA: out = E @ W + bias (16 rows per wave)
    {
      ushort (*o1)[136] = side ? bT : aT;
      ushort (*o2)[136] = side ? bcT : acT;
      int rbase = wave*16;
      for (int ct = 0; ct < 8; ++ct) {
        f32x4 p1 = {0.f,0.f,0.f,0.f}, p2 = {0.f,0.f,0.f,0.f};
#pragma unroll
        for (int ks = 0; ks < 4; ++ks) {
          bf16x8 ef1 = *(const bf16x8*)&E1[rbase + rloc][ks*32 + koff];
          bf16x8 ef2 = *(const bf16x8*)&E2[rbase + rloc][ks*32 + koff];
          bf16x8 wf  = *(const bf16x8*)&WT[ct*16 + rloc][ks*32 + koff];
          p1 = __builtin_amdgcn_mfma_f32_16x16x32_bf16(ef1, wf, p1, 0,0,0);
          p2 = __builtin_amdgcn_mfma_f32_16x16x32_bf16(ef2, wf, p2, 0,0,0);
        }
        int col = ct*16 + rloc;
        float bv = biasS[col];
#pragma unroll
        for (int r = 0; r < 4; ++r) {
          int row = rbase + (lane>>4)*4 + r;
          o1[row][col] = f2bf(p1[r] + bv);
          o2[row][col] = f2bf(p2[r] + bv);
        }
      }
    }
    __syncthreads();
  }

  // adjacency (R2/R6-verbatim)
  bf16x8 av[4], acv[4];
#pragma unroll
  for (int ks = 0; ks < 4; ++ks) {
    av[ks]  = *(const bf16x8*)&aT[wave*16 + rloc][ks*32 + koff];
    acv[ks] = *(const bf16x8*)&acT[wave*16 + rloc][ks*32 + koff];
  }
  f32x4 zf = {0.f,0.f,0.f,0.f};
  f32x4 acc[4], accc[4];
#pragma unroll
  for (int jt = 0; jt < 4; ++jt) { acc[jt] = zf; accc[jt] = zf; }
#pragma unroll
  for (int ks = 0; ks < 4; ++ks) {
#pragma unroll
    for (int jt = 0; jt < 4; ++jt) {
      bf16x8 bv  = *(const bf16x8*)&bT[jt*16 + rloc][ks*32 + koff];
      bf16x8 bcv = *(const bf16x8*)&bcT[jt*16 + rloc][ks*32 + koff];
      acc[jt]  = __builtin_amdgcn_mfma_f32_16x16x32_bf16(av[ks],  bv,  acc[jt],  0,0,0);
      accc[jt] = __builtin_amdgcn_mfma_f32_16x16x32_bf16(acv[ks], bcv, accc[jt], 0,0,0);
    }
  }
  int g = lane >> 4, c = lane & 15;
  float sq = 0.f;
#pragma unroll
  for (int r = 0; r < 4; ++r) {
    float mn = INFINITY; int mi = -1;
#pragma unroll
    for (int jt = 0; jt < 4; ++jt) {
      float v  = acc[jt][r]  * SCALE;
      float vc = accc[jt][r] * SCALE;
      float dd = v - vc;
      sq += dd*dd;
      int j = j0 + jt*16 + c;
      if (v < mn || (v == mn && j > mi)) { mn = v; mi = j; }
    }
#pragma unroll
    for (int msk = 1; msk < 16; msk <<= 1) {
      float ov = __shfl_xor(mn, msk);
      int   oi = __shfl_xor(mi, msk);
      if (ov < mn || (ov == mn && oi > mi)) { mn = ov; mi = oi; }
    }
    if (c == 0) {
      int gi = i0 + wave*16 + g*4 + r;
      minval[gi*8 + jy] = mn;
      minidx[gi*8 + jy] = mi;
    }
  }
  red[t] = sq;
  __syncthreads();
  for (int off = 128; off > 0; off >>= 1) {
    if (t < off) red[t] += red[t+off];
    __syncthreads();
  }
  if (t == 0) diffpart[(b*8 + jy)*8 + ix] = red[0];
}

// =============== K2: per-batch tail — MFMA x, coalesced P/Q ==============
__global__ __launch_bounds__(1024) void k_tail2(
    const float* __restrict__ inputs, const float* __restrict__ coords,
    const float* __restrict__ cc,
    const float* __restrict__ Wc, const float* __restrict__ bc,
    const float* __restrict__ Wcc, const float* __restrict__ bcc,
    const float* __restrict__ W1l, const float* __restrict__ b1l,
    const float* __restrict__ W1r,
    const float* __restrict__ minval, const int* __restrict__ minidx,
    const float* __restrict__ diffpart, const float* __restrict__ targets,
    const float* __restrict__ W2l, const float* __restrict__ b2l,
    const float* __restrict__ W2r,
    float* __restrict__ Pg, float* __restrict__ Qg, float* __restrict__ out) {
  __shared__ ushort W1lT[128][136], W1rT[128][136];
  __shared__ ushort xT[128][136];
  __shared__ ushort WBT[128][36];    // stacked [Wc(0..11); 0; Wcc(16..27); 0] transposed
  __shared__ ushort finB[128][36];   // packed [fin1(0..11) | 0 | -fin2(16..27) | 0]
  __shared__ float dbcS[128], headIn[12];
  __shared__ float xs[128], sbv[128];
  __shared__ float part[8][128];
  __shared__ int aminL[LL];
  __shared__ float dred[256];

  int b = blockIdx.x, t = threadIdx.x;
  int d = t & 127, h = t >> 7;      // h: 0..7
  int lane = t & 63, w = t >> 6;
  int rloc = lane & 15, koff = (lane >> 4) * 8;

  // T0: stage W1lT/W1rT, WBT, dbc, head
  for (int idx = t; idx < 16384; idx += 1024) {
    int kk = idx >> 7, dd2 = idx & 127;
    W1lT[dd2][kk] = f2bf(W1l[idx]);
    W1rT[dd2][kk] = f2bf(W1r[idx]);
  }
  for (int idx = t; idx < 4096; idx += 1024) {
    int d2 = idx >> 5, k = idx & 31;
    float v = 0.f;
    if (k < 12)                 v = Wc[k*DD + d2];
    else if (k >= 16 && k < 28) v = Wcc[(k-16)*DD + d2];
    WBT[d2][k] = f2bf(v);
  }
  if (t < 128) dbcS[t] = bc[t] - bcc[t];
  if (t < 12)  headIn[t] = (t < 10) ? inputs[(size_t)(b*LL)*10 + t] : 0.f;

  // T1: chunks of 128 rows: features -> x (MFMA) -> csx -> P,Q (MFMA)
  float csx = 0.f;
  for (int cch = 0; cch < 4; ++cch) {
    int rows0 = b*LL + cch*128;
    __syncthreads();   // prev chunk's xT readers done; T0 done before first use
    for (int idx = t; idx < 4096; idx += 1024) {
      int r = idx >> 5, k = idx & 31;
      int grow = rows0 + r;
      float v = 0.f;
      if (k < 10)                 v = inputs[(size_t)grow*10 + k];
      else if (k < 12)            v = coords[(size_t)grow*2 + (k-10)];
      else if (k >= 16 && k < 26) v = -(inputs[(size_t)grow*10 + (k-16)] - headIn[k-16]);
      else if (k >= 26 && k < 28) v = -cc[(size_t)grow*2 + (k-26)];
      finB[r][k] = f2bf(v);
    }
    __syncthreads();
    // x via MFMA: 64 tiles over 16 waves (4 each)
    {
      int rg = w >> 1;
      bf16x8 af = *(const bf16x8*)&finB[rg*16 + rloc][koff];
#pragma unroll
      for (int q = 0; q < 4; ++q) {
        int cg = (w & 1)*4 + q;
        bf16x8 wf = *(const bf16x8*)&WBT[cg*16 + rloc][koff];
        float bv = dbcS[cg*16 + rloc];
        f32x4 p = {bv, bv, bv, bv};
        p = __builtin_amdgcn_mfma_f32_16x16x32_bf16(af, wf, p, 0,0,0);
        int col = cg*16 + rloc;
#pragma unroll
        for (int r = 0; r < 4; ++r) {
          int row = rg*16 + (lane>>4)*4 + r;
          xT[row][col] = f2bf(p[r]);
        }
      }
    }
    __syncthreads();
    // csx: colsum partial of this chunk (16 bf16 LDS reads per thread)
#pragma unroll
    for (int rr = 0; rr < 16; ++rr) csx += bf2f(xT[h*16 + rr][d]);
    // P,Q via MFMA, swapped operands -> coalesced float4 stores
    {
      int rg = w & 7, mat = w >> 3;
      const ushort (*WTp)[136] = mat ? W1rT : W1lT;
      float* dst = mat ? Qg : Pg;
      int xrow = rows0 + rg*16 + rloc;
      for (int ct = 0; ct < 8; ++ct) {
        f32x4 p = {0.f,0.f,0.f,0.f};
#pragma unroll
        for (int ks = 0; ks < 4; ++ks) {
          bf16x8 wf = *(const bf16x8*)&WTp[ct*16 + rloc][ks*32 + koff];
          bf16x8 af = *(const bf16x8*)&xT[rg*16 + rloc][ks*32 + koff];
          p = __builtin_amdgcn_mfma_f32_16x16x32_bf16(wf, af, p, 0,0,0);
        }
        int wcol0 = ct*16 + (lane>>4)*4;
        *(float4*)&dst[(size_t)xrow*DD + wcol0] = make_float4(p[0], p[1], p[2], p[3]);
      }
    }
  }
  __syncthreads();

  // T2: colsum combine + argmin finalize
  part[h][d] = csx;
  if (t < LL) {
    int row = b*LL + t;
    float mv = minval[row*8]; int mi = minidx[row*8];
#pragma unroll
    for (int ch = 1; ch < 8; ++ch) {
      float v = minval[row*8 + ch]; int i2 = minidx[row*8 + ch];
      if (v < mv || (v == mv && i2 > mi)) { mv = v; mi = i2; }
    }
    aminL[t] = mi;
  }
  __syncthreads();
  if (h == 0) {
    float v = 0.f;
#pragma unroll
    for (int q = 0; q < 8; ++q) v += part[q][d];
    xs[d] = v;
  }
  __syncthreads();
  // T4: sb = colsum(x) @ W1l (f32 weights)
  {
    float acc = 0.f;
#pragma unroll
    for (int k = h*16; k < h*16 + 16; ++k) acc += xs[k] * W1l[k*DD + d];
    part[h][d] = acc;
  }
  __syncthreads();
  if (h == 0) {
    float v = 0.f;
#pragma unroll
    for (int q = 0; q < 8; ++q) v += part[q][d];
    sbv[d] = v;
  }
  __syncthreads();
  float base = sbv[d] * (1.0f/DEG) + b1l[d];
  // T6: stream h1, accumulate colsum(h1)
  float csum = 0.f;
  int l0 = h*64;
#pragma unroll 4
  for (int r = 0; r < 64; ++r) {
    int li = l0 + r;
    int am = aminL[li];
    float v = base - Pg[(size_t)am*DD + d] * (1.0f/DEG) + Qg[(size_t)(b*LL + li)*DD + d];
    csum += fmaxf(v, 0.f);
  }
  part[h][d] = csum;
  __syncthreads();
  if (h == 0) {
    float colsum = 0.f;
#pragma unroll
    for (int q = 0; q < 8; ++q) colsum += part[q][d];
    int amh = aminL[0];
    int am2 = aminL[amh - b*LL];
    float h1head = fmaxf(base - Pg[(size_t)amh*DD + d]*(1.0f/DEG) + Qg[(size_t)(b*LL)*DD + d], 0.f);
    float h1am   = fmaxf(base - Pg[(size_t)am2*DD + d]*(1.0f/DEG) + Qg[(size_t)amh*DD + d], 0.f);
    float agg = (colsum - h1am) * (1.0f/DEG);
    part[0][d] = agg * W2l[d] + h1head * W2r[d];
  }
  __syncthreads();
  if (t < 64) {
    float v = part[0][t] + part[0][t + 64];
#pragma unroll
    for (int msk = 32; msk > 0; msk >>= 1) v += __shfl_down(v, msk);
    if (t == 0) out[b] = v + b2l[0];
  }
  // T8: diff + targets (block 0)
  if (b == 0) {
    if (t < 256) dred[t] = diffpart[t];
    __syncthreads();
    for (int off = 128; off > 0; off >>= 1) {
      if (t < off) dred[t] += dred[t+off];
      __syncthreads();
    }
    if (t == 0) out[4] = dred[0] / (float)((float)BB*LL*LL);
    if (t < 4) out[5+t] = targets[t*LL];
  }
}

extern "C" void kernel_launch(void* const* d_in, const int* in_sizes, int n_in,
                              void* d_out, int out_size, void* d_ws, size_t ws_size,
                              hipStream_t stream) {
  const float* inputs  = (const float*)d_in[0];
  const float* coords  = (const float*)d_in[1];
  const float* targets = (const float*)d_in[2];
  const float* cc      = (const float*)d_in[3];
  const float* Wc  = (const float*)d_in[5];
  const float* bc  = (const float*)d_in[6];
  const float* Wcc = (const float*)d_in[7];
  const float* bcc = (const float*)d_in[8];
  const float* Wa  = (const float*)d_in[9];
  const float* ba  = (const float*)d_in[10];
  const float* Wb  = (const float*)d_in[11];
  const float* bb  = (const float*)d_in[12];
  const float* W1l = (const float*)d_in[13];
  const float* b1l = (const float*)d_in[14];
  const float* W1r = (const float*)d_in[15];
  const float* W2l = (const float*)d_in[16];
  const float* b2l = (const float*)d_in[17];
  const float* W2r = (const float*)d_in[18];
  float* out = (float*)d_out;

  float* ws = (float*)d_ws;
  float* Pg = ws;                                  // NROW*DD
  float* Qg = ws + (size_t)NROW*DD;                // NROW*DD
  float* diffpart = ws + (size_t)2*NROW*DD;        // 256
  float* minval   = diffpart + 256;                // NROW*8
  int*   minidx   = (int*)(minval + (size_t)NROW*8);

  k_fused<<<dim3(8, 8, 4), 256, 0, stream>>>(inputs, coords, cc, Wc, bc, Wcc, bcc,
                                             Wa, ba, Wb, bb, diffpart, minval, minidx);
  k_tail2<<<4, 1024, 0, stream>>>(inputs, coords, cc, Wc, bc, Wcc, bcc,
                                  W1l, b1l, W1r, minval, minidx, diffpart, targets,
                                  W2l, b2l, W2r, Pg, Qg, out);
}

// Round 9
// 48.921 us; speedup vs baseline: 1.5766x; 1.4550x over previous
//
#include <hip/hip_runtime.h>
#include <math.h>

#define BB 4
#define LL 512
#define NROW (BB*LL)      // 2048
#define DD 128
#define DEG 511.0f
#define SCALE 0.08838834764831845f   // 1/sqrt(128)

typedef short bf16x8 __attribute__((ext_vector_type(8)));
typedef float f32x4 __attribute__((ext_vector_type(4)));

static __device__ __forceinline__ ushort f2bf(float f) {
  unsigned u = __float_as_uint(f);
  u = (u + 0x7fffu + ((u >> 16) & 1u)) >> 16;   // RNE
  return (ushort)u;
}

// =============== K1: fused front+adjacency, MFMA embeddings (R8-verbatim) ===============
__global__ __launch_bounds__(256) void k_fused(
    const float* __restrict__ inputs, const float* __restrict__ coords,
    const float* __restrict__ cc,
    const float* __restrict__ Wc, const float* __restrict__ bc,
    const float* __restrict__ Wcc, const float* __restrict__ bcc,
    const float* __restrict__ Wa, const float* __restrict__ ba,
    const float* __restrict__ Wb, const float* __restrict__ bb,
    float* __restrict__ diffpart, float* __restrict__ minval, int* __restrict__ minidx) {
  __shared__ ushort E1[64][136], E2[64][136];
  __shared__ ushort aT[64][136], acT[64][136], bT[64][136], bcT[64][136];
  __shared__ ushort WcT[128][36], WccT[128][36];
  __shared__ float bcS[128], bccS[128], biasS[128], headIn[12];
  __shared__ float red[256];
  __shared__ __align__(16) char uni[34816];
  ushort (*WT)[136] = (ushort(*)[136])uni;
  ushort (*fin1B)[32] = (ushort(*)[32])uni;
  ushort (*fin2B)[32] = (ushort(*)[32])(uni + 4096);

  int t = threadIdx.x;
  int ix = blockIdx.x, jy = blockIdx.y, b = blockIdx.z;
  int i0 = b*LL + ix*64, j0 = b*LL + jy*64;
  int lane = t & 63, wave = t >> 6;
  int rloc = lane & 15, koff = (lane >> 4) * 8;

  for (int idx = t; idx < 4096; idx += 256) {
    int d2 = idx >> 5, k = idx & 31;
    WcT[d2][k]  = (k < 12) ? f2bf(Wc[k*DD + d2])  : 0;
    WccT[d2][k] = (k < 12) ? f2bf(Wcc[k*DD + d2]) : 0;
  }
  if (t < 128) { bcS[t] = bc[t]; bccS[t] = bcc[t]; }
  if (t < 12)  headIn[t] = (t < 10) ? inputs[(size_t)(b*LL)*10 + t] : 0.f;
  __syncthreads();

  for (int side = 0; side < 2; ++side) {
    int rows0 = side ? j0 : i0;
    const float* W    = side ? Wb : Wa;
    const float* bias = side ? bb : ba;
    for (int idx = t; idx < 2048; idx += 256) {
      int r = idx >> 5, k = idx & 31;
      int grow = rows0 + r;
      float f1 = 0.f, f2 = 0.f;
      if (k < 10)      { f1 = inputs[(size_t)grow*10 + k]; f2 = f1 - headIn[k]; }
      else if (k < 12) { f1 = coords[(size_t)grow*2 + (k-10)]; f2 = cc[(size_t)grow*2 + (k-10)]; }
      fin1B[r][k] = f2bf(f1);
      fin2B[r][k] = f2bf(f2);
    }
    __syncthreads();
    {
      int rg = wave;
      bf16x8 af1 = *(const bf16x8*)&fin1B[rg*16 + rloc][koff];
      bf16x8 af2 = *(const bf16x8*)&fin2B[rg*16 + rloc][koff];
      for (int cg = 0; cg < 8; ++cg) {
        bf16x8 wf1 = *(const bf16x8*)&WcT[cg*16 + rloc][koff];
        bf16x8 wf2 = *(const bf16x8*)&WccT[cg*16 + rloc][koff];
        float bv1 = bcS[cg*16 + rloc], bv2 = bccS[cg*16 + rloc];
        f32x4 p1 = {bv1, bv1, bv1, bv1};
        f32x4 p2 = {bv2, bv2, bv2, bv2};
        p1 = __builtin_amdgcn_mfma_f32_16x16x32_bf16(af1, wf1, p1, 0,0,0);
        p2 = __builtin_amdgcn_mfma_f32_16x16x32_bf16(af2, wf2, p2, 0,0,0);
        int col = cg*16 + rloc;
#pragma unroll
        for (int r = 0; r < 4; ++r) {
          int row = rg*16 + (lane>>4)*4 + r;
          E1[row][col] = f2bf(p1[r]);
          E2[row][col] = f2bf(p2[r]);
        }
      }
    }
    __syncthreads();
    for (int idx = t; idx < 16384; idx += 256) {
      int kk = idx >> 7, dd = idx & 127;
      WT[dd][kk] = f2bf(W[idx]);
    }
    if (t < 128) biasS[t] = bias[t];
    __syncthreads();
    {
      ushort (*o1)[136] = side ? bT : aT;
      ushort (*o2)[136] = side ? bcT : acT;
      int rbase = wave*16;
      for (int ct = 0; ct < 8; ++ct) {
        f32x4 p1 = {0.f,0.f,0.f,0.f}, p2 = {0.f,0.f,0.f,0.f};
#pragma unroll
        for (int ks = 0; ks < 4; ++ks) {
          bf16x8 ef1 = *(const bf16x8*)&E1[rbase + rloc][ks*32 + koff];
          bf16x8 ef2 = *(const bf16x8*)&E2[rbase + rloc][ks*32 + koff];
          bf16x8 wf  = *(const bf16x8*)&WT[ct*16 + rloc][ks*32 + koff];
          p1 = __builtin_amdgcn_mfma_f32_16x16x32_bf16(ef1, wf, p1, 0,0,0);
          p2 = __builtin_amdgcn_mfma_f32_16x16x32_bf16(ef2, wf, p2, 0,0,0);
        }
        int col = ct*16 + rloc;
        float bv = biasS[col];
#pragma unroll
        for (int r = 0; r < 4; ++r) {
          int row = rbase + (lane>>4)*4 + r;
          o1[row][col] = f2bf(p1[r] + bv);
          o2[row][col] = f2bf(p2[r] + bv);
        }
      }
    }
    __syncthreads();
  }

  bf16x8 av[4], acv[4];
#pragma unroll
  for (int ks = 0; ks < 4; ++ks) {
    av[ks]  = *(const bf16x8*)&aT[wave*16 + rloc][ks*32 + koff];
    acv[ks] = *(const bf16x8*)&acT[wave*16 + rloc][ks*32 + koff];
  }
  f32x4 zf = {0.f,0.f,0.f,0.f};
  f32x4 acc[4], accc[4];
#pragma unroll
  for (int jt = 0; jt < 4; ++jt) { acc[jt] = zf; accc[jt] = zf; }
#pragma unroll
  for (int ks = 0; ks < 4; ++ks) {
#pragma unroll
    for (int jt = 0; jt < 4; ++jt) {
      bf16x8 bv  = *(const bf16x8*)&bT[jt*16 + rloc][ks*32 + koff];
      bf16x8 bcv = *(const bf16x8*)&bcT[jt*16 + rloc][ks*32 + koff];
      acc[jt]  = __builtin_amdgcn_mfma_f32_16x16x32_bf16(av[ks],  bv,  acc[jt],  0,0,0);
      accc[jt] = __builtin_amdgcn_mfma_f32_16x16x32_bf16(acv[ks], bcv, accc[jt], 0,0,0);
    }
  }
  int g = lane >> 4, c = lane & 15;
  float sq = 0.f;
#pragma unroll
  for (int r = 0; r < 4; ++r) {
    float mn = INFINITY; int mi = -1;
#pragma unroll
    for (int jt = 0; jt < 4; ++jt) {
      float v  = acc[jt][r]  * SCALE;
      float vc = accc[jt][r] * SCALE;
      float dd = v - vc;
      sq += dd*dd;
      int j = j0 + jt*16 + c;
      if (v < mn || (v == mn && j > mi)) { mn = v; mi = j; }
    }
#pragma unroll
    for (int msk = 1; msk < 16; msk <<= 1) {
      float ov = __shfl_xor(mn, msk);
      int   oi = __shfl_xor(mi, msk);
      if (ov < mn || (ov == mn && oi > mi)) { mn = ov; mi = oi; }
    }
    if (c == 0) {
      int gi = i0 + wave*16 + g*4 + r;
      minval[gi*8 + jy] = mn;
      minidx[gi*8 + jy] = mi;
    }
  }
  red[t] = sq;
  __syncthreads();
  for (int off = 128; off > 0; off >>= 1) {
    if (t < off) red[t] += red[t+off];
    __syncthreads();
  }
  if (t == 0) diffpart[(b*8 + jy)*8 + ix] = red[0];
}

// =============== K2: x + P,Q + xpart (R2 k_front m==2 branch, 128 blocks) ===============
__global__ __launch_bounds__(256) void k_pq(
    const float* __restrict__ inputs, const float* __restrict__ coords,
    const float* __restrict__ cc,
    const float* __restrict__ Wc, const float* __restrict__ bc,
    const float* __restrict__ Wcc, const float* __restrict__ bcc,
    const float* __restrict__ W1l, const float* __restrict__ W1r,
    float* __restrict__ P, float* __restrict__ Q, float* __restrict__ xpart) {
  int bx = blockIdx.x;
  int t = threadIdx.x;
  int row0 = bx * 16;
  int b = bx >> 5;
  __shared__ float fin1[16][12], fin2[16][12];
  __shared__ float Es[16][132];
  __shared__ float cs[2][128];
  if (t < 192) {
    int r = t / 12, k = t % 12;
    int row = row0 + r;
    float v1, v2;
    if (k < 10) {
      float v = inputs[row*10 + k];
      v1 = v;
      v2 = v - inputs[(b*LL)*10 + k];
    } else {
      v1 = coords[row*2 + (k-10)];
      v2 = cc[row*2 + (k-10)];
    }
    fin1[r][k] = v1;
    fin2[r][k] = v2;
  }
  __syncthreads();
  for (int it = 0; it < 8; ++it) {
    int idx = t + it*256;
    int r = idx >> 7, d = idx & 127;
    float e1 = bc[d], e2 = bcc[d];
#pragma unroll
    for (int k = 0; k < 12; ++k) {
      e1 += fin1[r][k] * Wc[k*DD + d];
      e2 += fin2[r][k] * Wcc[k*DD + d];
    }
    Es[r][d] = e1 - e2;
  }
  __syncthreads();
  {   // colsum(x) partial over these 16 rows
    int d = t & 127, h = t >> 7;
    float s = 0.f;
#pragma unroll
    for (int r = 0; r < 8; ++r) s += Es[h*8 + r][d];
    cs[h][d] = s;
    __syncthreads();
    if (h == 0) xpart[bx*DD + d] = cs[0][d] + cs[1][d];
  }
  int tx = t & 31, ty = t >> 5;
  int d0 = tx*4, r0 = ty*2;
  float aU0[4]={0,0,0,0}, aU1[4]={0,0,0,0}, aV0[4]={0,0,0,0}, aV1[4]={0,0,0,0};
#pragma unroll 4
  for (int k = 0; k < DD; ++k) {
    float4 u = *(const float4*)&W1l[k*DD + d0];
    float4 v = *(const float4*)&W1r[k*DD + d0];
    float e0 = Es[r0][k], e1 = Es[r0+1][k];
    aU0[0]+=e0*u.x; aU0[1]+=e0*u.y; aU0[2]+=e0*u.z; aU0[3]+=e0*u.w;
    aU1[0]+=e1*u.x; aU1[1]+=e1*u.y; aU1[2]+=e1*u.z; aU1[3]+=e1*u.w;
    aV0[0]+=e0*v.x; aV0[1]+=e0*v.y; aV0[2]+=e0*v.z; aV0[3]+=e0*v.w;
    aV1[0]+=e1*v.x; aV1[1]+=e1*v.y; aV1[2]+=e1*v.z; aV1[3]+=e1*v.w;
  }
  *(float4*)&P[(row0+r0)*DD + d0]   = make_float4(aU0[0],aU0[1],aU0[2],aU0[3]);
  *(float4*)&P[(row0+r0+1)*DD + d0] = make_float4(aU1[0],aU1[1],aU1[2],aU1[3]);
  *(float4*)&Q[(row0+r0)*DD + d0]   = make_float4(aV0[0],aV0[1],aV0[2],aV0[3]);
  *(float4*)&Q[(row0+r0+1)*DD + d0] = make_float4(aV1[0],aV1[1],aV1[2],aV1[3]);
}

// =============== K3: argmin finalize + sb + h1 + h1part (64 blocks) ===============
__global__ __launch_bounds__(256) void k_h1(
    const float* __restrict__ P, const float* __restrict__ Q,
    const float* __restrict__ xpart, const float* __restrict__ W1l,
    const float* __restrict__ b1l,
    const float* __restrict__ minval, const int* __restrict__ minidx,
    float* __restrict__ h1, float* __restrict__ h1part, int* __restrict__ amin) {
  int bx = blockIdx.x, t = threadIdx.x;   // bx: 0..63, 32 rows each
  int b = bx >> 4;
  int d = t & 127, h = t >> 7;
  __shared__ int aminL[32];
  __shared__ float xs[128];
  __shared__ float cs[2][128];
  // argmin finalize for this block's 32 rows
  if (t < 32) {
    int row = bx*32 + t;
    float mv = minval[row*8]; int mi = minidx[row*8];
#pragma unroll
    for (int ch = 1; ch < 8; ++ch) {
      float v = minval[row*8 + ch]; int i2 = minidx[row*8 + ch];
      if (v < mv || (v == mv && i2 > mi)) { mv = v; mi = i2; }
    }
    aminL[t] = mi;
    amin[row] = mi;
  }
  // colsum(x) for batch b from xpart rows b*32..b*32+31
  {
    float s = 0.f;
#pragma unroll
    for (int i = 0; i < 16; ++i) s += xpart[(b*32 + h*16 + i)*DD + d];
    cs[h][d] = s;
  }
  __syncthreads();   // covers aminL + cs
  if (h == 0) xs[d] = cs[0][d] + cs[1][d];
  __syncthreads();
  // sb GEMV: thread (d,h) covers k in [h*64, h*64+64)
  {
    float acc = 0.f;
    for (int k = h*64; k < h*64 + 64; ++k) acc += xs[k] * W1l[k*DD + d];
    cs[h][d] = acc;
  }
  __syncthreads();
  float sbv = cs[0][d] + cs[1][d];
  __syncthreads();   // all reads of cs done before reuse
  float base = sbv * (1.0f/DEG) + b1l[d];
  float ps = 0.f;
#pragma unroll 4
  for (int rr = 0; rr < 16; ++rr) {
    int li = h*16 + rr;
    int i = bx*32 + li;
    int am = aminL[li];
    float v = base - P[(size_t)am*DD + d] * (1.0f/DEG) + Q[(size_t)i*DD + d];
    v = fmaxf(v, 0.f);
    h1[(size_t)i*DD + d] = v;
    ps += v;
  }
  cs[h][d] = ps;
  __syncthreads();
  if (h == 0) h1part[bx*DD + d] = cs[0][d] + cs[1][d];
}

// =============== K4: final layer + diff + targets (4 blocks) ===============
__global__ __launch_bounds__(128) void k_final(
    const float* __restrict__ h1, const float* __restrict__ h1part,
    const int* __restrict__ amin,
    const float* __restrict__ W2l, const float* __restrict__ b2l,
    const float* __restrict__ W2r,
    const float* __restrict__ diffpart, const float* __restrict__ targets,
    float* __restrict__ out) {
  int b = blockIdx.x, d = threadIdx.x;
  float s = 0.f;
#pragma unroll
  for (int p = 0; p < 16; ++p) s += h1part[(b*16 + p)*DD + d];
  int am = amin[b*LL];
  float agg = (s - h1[(size_t)am*DD + d]) * (1.0f/DEG);
  float v = agg * W2l[d] + h1[(size_t)(b*LL)*DD + d] * W2r[d];
  __shared__ float red[128];
  red[d] = v;
  __syncthreads();
  for (int off = 64; off > 0; off >>= 1) {
    if (d < off) red[d] += red[d+off];
    __syncthreads();
  }
  if (d == 0) out[b] = red[0] + b2l[0];
  if (b == 0) {
    __shared__ float dred[128];
    dred[d] = diffpart[d] + diffpart[d + 128];
    __syncthreads();
    for (int off = 64; off > 0; off >>= 1) {
      if (d < off) dred[d] += dred[d+off];
      __syncthreads();
    }
    if (d == 0) out[4] = dred[0] / (float)((float)BB*LL*LL);
    if (d < 4) out[5+d] = targets[d*LL];
  }
}

extern "C" void kernel_launch(void* const* d_in, const int* in_sizes, int n_in,
                              void* d_out, int out_size, void* d_ws, size_t ws_size,
                              hipStream_t stream) {
  const float* inputs  = (const float*)d_in[0];
  const float* coords  = (const float*)d_in[1];
  const float* targets = (const float*)d_in[2];
  const float* cc      = (const float*)d_in[3];
  const float* Wc  = (const float*)d_in[5];
  const float* bc  = (const float*)d_in[6];
  const float* Wcc = (const float*)d_in[7];
  const float* bcc = (const float*)d_in[8];
  const float* Wa  = (const float*)d_in[9];
  const float* ba  = (const float*)d_in[10];
  const float* Wb  = (const float*)d_in[11];
  const float* bb  = (const float*)d_in[12];
  const float* W1l = (const float*)d_in[13];
  const float* b1l = (const float*)d_in[14];
  const float* W1r = (const float*)d_in[15];
  const float* W2l = (const float*)d_in[16];
  const float* b2l = (const float*)d_in[17];
  const float* W2r = (const float*)d_in[18];
  float* out = (float*)d_out;

  float* ws = (float*)d_ws;
  float* Pg = ws;                                  // NROW*DD
  float* Qg = ws + (size_t)NROW*DD;                // NROW*DD
  float* h1 = ws + (size_t)2*NROW*DD;              // NROW*DD
  float* xpart    = ws + (size_t)3*NROW*DD;        // 128*DD
  float* h1part   = xpart + 128*DD;                // 64*DD
  float* diffpart = h1part + 64*DD;                // 256
  float* minval   = diffpart + 256;                // NROW*8
  int*   minidx   = (int*)(minval + (size_t)NROW*8);
  int*   amin     = minidx + (size_t)NROW*8;       // NROW

  k_fused<<<dim3(8, 8, 4), 256, 0, stream>>>(inputs, coords, cc, Wc, bc, Wcc, bcc,
                                             Wa, ba, Wb, bb, diffpart, minval, minidx);
  k_pq   <<<128, 256, 0, stream>>>(inputs, coords, cc, Wc, bc, Wcc, bcc,
                                   W1l, W1r, Pg, Qg, xpart);
  k_h1   <<<64, 256, 0, stream>>>(Pg, Qg, xpart, W1l, b1l, minval, minidx,
                                  h1, h1part, amin);
  k_final<<<4, 128, 0, stream>>>(h1, h1part, amin, W2l, b2l, W2r,
                                 diffpart, targets, out);
}

// Round 10
// 42.135 us; speedup vs baseline: 1.8305x; 1.1611x over previous
//
#include <hip/hip_runtime.h>
#include <math.h>

#define BB 4
#define LL 512
#define NROW (BB*LL)      // 2048
#define DD 128
#define DEG 511.0f
#define SCALE 0.08838834764831845f   // 1/sqrt(128)
#define INVN (1.0f/((float)BB*LL*LL))

typedef short bf16x8 __attribute__((ext_vector_type(8)));
typedef float f32x4 __attribute__((ext_vector_type(4)));

static __device__ __forceinline__ ushort f2bf(float f) {
  unsigned u = __float_as_uint(f);
  u = (u + 0x7fffu + ((u >> 16) & 1u)) >> 16;   // RNE
  return (ushort)u;
}

// ---------------- K1: embed + 6 projections + colsum(x) partials + out init ----------------
__global__ __launch_bounds__(256) void k_front(
    const float* __restrict__ inputs, const float* __restrict__ coords,
    const float* __restrict__ cc, const float* __restrict__ targets,
    const float* __restrict__ Wc, const float* __restrict__ bc,
    const float* __restrict__ Wcc, const float* __restrict__ bcc,
    const float* __restrict__ Wa, const float* __restrict__ ba,
    const float* __restrict__ Wb, const float* __restrict__ bb,
    const float* __restrict__ W1l, const float* __restrict__ W1r,
    ushort* __restrict__ bfA, ushort* __restrict__ bfB,
    ushort* __restrict__ bfAc, ushort* __restrict__ bfBc,
    float* __restrict__ P, float* __restrict__ Q,
    float* __restrict__ xpart, float* __restrict__ out) {
  int bx = blockIdx.x, m = blockIdx.y;
  int t = threadIdx.x;
  if (m == 2 && bx == 0) {           // init outputs (kernel boundary orders vs K2/K3 atomics)
    if (t < 5) out[t] = 0.f;
    if (t >= 8 && t < 12) out[5 + (t-8)] = targets[(t-8)*LL];
  }
  int row0 = bx * 16;
  int b = bx >> 5;
  __shared__ float fin1[16][12], fin2[16][12];
  __shared__ float Es[16][132];
  __shared__ float cs[2][128];
  if (t < 192) {
    int r = t / 12, k = t % 12;
    int row = row0 + r;
    float v1, v2;
    if (k < 10) {
      float v = inputs[row*10 + k];
      v1 = v;
      v2 = v - inputs[(b*LL)*10 + k];
    } else {
      v1 = coords[row*2 + (k-10)];
      v2 = cc[row*2 + (k-10)];
    }
    fin1[r][k] = v1;
    fin2[r][k] = v2;
  }
  __syncthreads();
  for (int it = 0; it < 8; ++it) {
    int idx = t + it*256;
    int r = idx >> 7, d = idx & 127;
    float e;
    if (m == 0) {
      e = bc[d];
#pragma unroll
      for (int k = 0; k < 12; ++k) e += fin1[r][k] * Wc[k*DD + d];
    } else if (m == 1) {
      e = bcc[d];
#pragma unroll
      for (int k = 0; k < 12; ++k) e += fin2[r][k] * Wcc[k*DD + d];
    } else {
      float e1 = bc[d], e2 = bcc[d];
#pragma unroll
      for (int k = 0; k < 12; ++k) {
        e1 += fin1[r][k] * Wc[k*DD + d];
        e2 += fin2[r][k] * Wcc[k*DD + d];
      }
      e = e1 - e2;
    }
    Es[r][d] = e;
  }
  __syncthreads();
  if (m == 2) {   // colsum(x) partial over these 16 rows
    int d = t & 127, h = t >> 7;
    float s = 0.f;
#pragma unroll
    for (int r = 0; r < 8; ++r) s += Es[h*8 + r][d];
    cs[h][d] = s;
    __syncthreads();
    if (h == 0) xpart[bx*DD + d] = cs[0][d] + cs[1][d];
  }
  const float* U = (m == 2) ? W1l : Wa;
  const float* V = (m == 2) ? W1r : Wb;
  int tx = t & 31, ty = t >> 5;
  int d0 = tx*4, r0 = ty*2;
  float aU0[4]={0,0,0,0}, aU1[4]={0,0,0,0}, aV0[4]={0,0,0,0}, aV1[4]={0,0,0,0};
#pragma unroll 4
  for (int k = 0; k < DD; ++k) {
    float4 u = *(const float4*)&U[k*DD + d0];
    float4 v = *(const float4*)&V[k*DD + d0];
    float e0 = Es[r0][k], e1 = Es[r0+1][k];
    aU0[0]+=e0*u.x; aU0[1]+=e0*u.y; aU0[2]+=e0*u.z; aU0[3]+=e0*u.w;
    aU1[0]+=e1*u.x; aU1[1]+=e1*u.y; aU1[2]+=e1*u.z; aU1[3]+=e1*u.w;
    aV0[0]+=e0*v.x; aV0[1]+=e0*v.y; aV0[2]+=e0*v.z; aV0[3]+=e0*v.w;
    aV1[0]+=e1*v.x; aV1[1]+=e1*v.y; aV1[2]+=e1*v.z; aV1[3]+=e1*v.w;
  }
  if (m < 2) {
    float4 bu = *(const float4*)&ba[d0];
    float4 bw = *(const float4*)&bb[d0];
    ushort* dU = (m == 0) ? bfA : bfAc;
    ushort* dV = (m == 0) ? bfB : bfBc;
    ushort4 o;
    o = make_ushort4(f2bf(aU0[0]+bu.x), f2bf(aU0[1]+bu.y), f2bf(aU0[2]+bu.z), f2bf(aU0[3]+bu.w));
    *(ushort4*)&dU[(row0+r0)*DD + d0] = o;
    o = make_ushort4(f2bf(aU1[0]+bu.x), f2bf(aU1[1]+bu.y), f2bf(aU1[2]+bu.z), f2bf(aU1[3]+bu.w));
    *(ushort4*)&dU[(row0+r0+1)*DD + d0] = o;
    o = make_ushort4(f2bf(aV0[0]+bw.x), f2bf(aV0[1]+bw.y), f2bf(aV0[2]+bw.z), f2bf(aV0[3]+bw.w));
    *(ushort4*)&dV[(row0+r0)*DD + d0] = o;
    o = make_ushort4(f2bf(aV1[0]+bw.x), f2bf(aV1[1]+bw.y), f2bf(aV1[2]+bw.z), f2bf(aV1[3]+bw.w));
    *(ushort4*)&dV[(row0+r0+1)*DD + d0] = o;
  } else {
    *(float4*)&P[(row0+r0)*DD + d0]   = make_float4(aU0[0],aU0[1],aU0[2],aU0[3]);
    *(float4*)&P[(row0+r0+1)*DD + d0] = make_float4(aU1[0],aU1[1],aU1[2],aU1[3]);
    *(float4*)&Q[(row0+r0)*DD + d0]   = make_float4(aV0[0],aV0[1],aV0[2],aV0[3]);
    *(float4*)&Q[(row0+r0+1)*DD + d0] = make_float4(aV1[0],aV1[1],aV1[2],aV1[3]);
  }
}

// ---------------- K2: MFMA adjacency (R2 core) + atomic diff ----------------
__global__ __launch_bounds__(256) void k_adj(
    const ushort* __restrict__ bfA, const ushort* __restrict__ bfB,
    const ushort* __restrict__ bfAc, const ushort* __restrict__ bfBc,
    float* __restrict__ minval, int* __restrict__ minidx, float* __restrict__ out) {
  __shared__ ushort Bs[64][136], Bcs[64][136];
  __shared__ float red[256];
  int t = threadIdx.x;
  int ix = blockIdx.x, jy = blockIdx.y, b = blockIdx.z;
  int i0 = b*LL + ix*64, j0 = b*LL + jy*64;
  int wave = t >> 6, lane = t & 63;
  int rowA = i0 + wave*16 + (lane & 15);
  int koff = (lane >> 4) * 8;
  bf16x8 av[4], acv[4];
#pragma unroll
  for (int ks = 0; ks < 4; ++ks) {
    av[ks]  = *(const bf16x8*)&bfA[(size_t)rowA*DD + ks*32 + koff];
    acv[ks] = *(const bf16x8*)&bfAc[(size_t)rowA*DD + ks*32 + koff];
  }
  for (int it = 0; it < 4; ++it) {
    int chunk = t + it*256;
    int row = chunk >> 4, c4 = chunk & 15;
    *(uint4*)&Bs[row][c4*8]  = *(const uint4*)&bfB[(size_t)(j0+row)*DD + c4*8];
    *(uint4*)&Bcs[row][c4*8] = *(const uint4*)&bfBc[(size_t)(j0+row)*DD + c4*8];
  }
  __syncthreads();
  f32x4 zf = {0.f, 0.f, 0.f, 0.f};
  f32x4 acc[4], accc[4];
#pragma unroll
  for (int jt = 0; jt < 4; ++jt) { acc[jt] = zf; accc[jt] = zf; }
#pragma unroll
  for (int ks = 0; ks < 4; ++ks) {
#pragma unroll
    for (int jt = 0; jt < 4; ++jt) {
      bf16x8 bv  = *(const bf16x8*)&Bs[jt*16 + (lane&15)][ks*32 + koff];
      bf16x8 bcv = *(const bf16x8*)&Bcs[jt*16 + (lane&15)][ks*32 + koff];
      acc[jt]  = __builtin_amdgcn_mfma_f32_16x16x32_bf16(av[ks],  bv,  acc[jt],  0,0,0);
      accc[jt] = __builtin_amdgcn_mfma_f32_16x16x32_bf16(acv[ks], bcv, accc[jt], 0,0,0);
    }
  }
  int g = lane >> 4, c = lane & 15;
  float sq = 0.f;
#pragma unroll
  for (int r = 0; r < 4; ++r) {
    float mn = INFINITY; int mi = -1;
#pragma unroll
    for (int jt = 0; jt < 4; ++jt) {
      float v  = acc[jt][r]  * SCALE;
      float vc = accc[jt][r] * SCALE;
      float d = v - vc;
      sq += d*d;
      int j = j0 + jt*16 + c;
      if (v < mn || (v == mn && j > mi)) { mn = v; mi = j; }
    }
#pragma unroll
    for (int msk = 1; msk < 16; msk <<= 1) {
      float ov = __shfl_xor(mn, msk);
      int   oi = __shfl_xor(mi, msk);
      if (ov < mn || (ov == mn && oi > mi)) { mn = ov; mi = oi; }
    }
    if (c == 0) {
      int gi = i0 + wave*16 + g*4 + r;
      minval[gi*8 + jy] = mn;
      minidx[gi*8 + jy] = mi;
    }
  }
  red[t] = sq;
  __syncthreads();
  for (int off = 128; off > 0; off >>= 1) {
    if (t < off) red[t] += red[t+off];
    __syncthreads();
  }
  if (t == 0) atomicAdd(&out[4], red[0] * INVN);
}

// ---------------- K3: argmin finalize + sb + h1-in-registers + atomic out[b] -----------
__global__ __launch_bounds__(256) void k_tail(
    const float* __restrict__ P, const float* __restrict__ Q,
    const float* __restrict__ xpart, const float* __restrict__ W1l,
    const float* __restrict__ b1l,
    const float* __restrict__ minval, const int* __restrict__ minidx,
    const float* __restrict__ W2l, const float* __restrict__ b2l,
    const float* __restrict__ W2r, float* __restrict__ out) {
  int bx = blockIdx.x, t = threadIdx.x;   // bx: 0..63, 32 rows each
  int b = bx >> 4;
  int d = t & 127, h = t >> 7;
  __shared__ int aminL[32];
  __shared__ float xs[128];
  __shared__ float cs[2][128];
  __shared__ float red[256];
  // argmin finalize for this block's 32 rows
  if (t < 32) {
    int row = bx*32 + t;
    float mv = minval[row*8]; int mi = minidx[row*8];
#pragma unroll
    for (int ch = 1; ch < 8; ++ch) {
      float v = minval[row*8 + ch]; int i2 = minidx[row*8 + ch];
      if (v < mv || (v == mv && i2 > mi)) { mv = v; mi = i2; }
    }
    aminL[t] = mi;
  }
  // colsum(x) for batch b from xpart rows b*32..b*32+31
  {
    float s = 0.f;
#pragma unroll
    for (int i = 0; i < 16; ++i) s += xpart[(b*32 + h*16 + i)*DD + d];
    cs[h][d] = s;
  }
  __syncthreads();   // covers aminL + cs
  if (h == 0) xs[d] = cs[0][d] + cs[1][d];
  __syncthreads();
  // sb GEMV: thread (d,h) covers k in [h*64, h*64+64)
  {
    float acc = 0.f;
    for (int k = h*64; k < h*64 + 64; ++k) acc += xs[k] * W1l[k*DD + d];
    cs[h][d] = acc;
  }
  __syncthreads();
  float sbv = cs[0][d] + cs[1][d];
  float base = sbv * (1.0f/DEG) + b1l[d];
  // h1 rows in registers; ps = sum over this thread's 16 rows
  float ps = 0.f;
#pragma unroll 4
  for (int rr = 0; rr < 16; ++rr) {
    int li = h*16 + rr;
    int i = bx*32 + li;
    int am = aminL[li];
    float v = base - P[(size_t)am*DD + d] * (1.0f/DEG) + Q[(size_t)i*DD + d];
    ps += fmaxf(v, 0.f);
  }
  float w2l = W2l[d];
  float contrib = ps * w2l * (1.0f/DEG);
  // head-owning block adds the correction terms
  if ((bx & 15) == 0 && h == 0) {
    int amh = aminL[0];                      // argmin of head row (global row idx)
    float mv = minval[amh*8]; int am2 = minidx[amh*8];
#pragma unroll
    for (int ch = 1; ch < 8; ++ch) {
      float v = minval[amh*8 + ch]; int i2 = minidx[amh*8 + ch];
      if (v < mv || (v == mv && i2 > am2)) { mv = v; am2 = i2; }
    }
    float h1amh  = fmaxf(base - P[(size_t)am2*DD + d]*(1.0f/DEG) + Q[(size_t)amh*DD + d], 0.f);
    float h1head = fmaxf(base - P[(size_t)amh*DD + d]*(1.0f/DEG) + Q[(size_t)(b*LL)*DD + d], 0.f);
    contrib += -h1amh * (1.0f/DEG) * w2l + h1head * W2r[d];
  }
  red[t] = contrib;
  __syncthreads();
  for (int off = 128; off > 0; off >>= 1) {
    if (t < off) red[t] += red[t+off];
    __syncthreads();
  }
  if (t == 0) atomicAdd(&out[b], red[0] + (((bx & 15) == 0) ? b2l[0] : 0.f));
}

extern "C" void kernel_launch(void* const* d_in, const int* in_sizes, int n_in,
                              void* d_out, int out_size, void* d_ws, size_t ws_size,
                              hipStream_t stream) {
  const float* inputs  = (const float*)d_in[0];
  const float* coords  = (const float*)d_in[1];
  const float* targets = (const float*)d_in[2];
  const float* cc      = (const float*)d_in[3];
  const float* Wc  = (const float*)d_in[5];
  const float* bc  = (const float*)d_in[6];
  const float* Wcc = (const float*)d_in[7];
  const float* bcc = (const float*)d_in[8];
  const float* Wa  = (const float*)d_in[9];
  const float* ba  = (const float*)d_in[10];
  const float* Wb  = (const float*)d_in[11];
  const float* bb  = (const float*)d_in[12];
  const float* W1l = (const float*)d_in[13];
  const float* b1l = (const float*)d_in[14];
  const float* W1r = (const float*)d_in[15];
  const float* W2l = (const float*)d_in[16];
  const float* b2l = (const float*)d_in[17];
  const float* W2r = (const float*)d_in[18];
  float* out = (float*)d_out;

  float* ws = (float*)d_ws;
  float* Pg = ws;                                  // NROW*DD
  float* Qg = ws + (size_t)NROW*DD;                // NROW*DD
  ushort* bfA  = (ushort*)(ws + (size_t)2*NROW*DD);
  ushort* bfB  = bfA  + (size_t)NROW*DD;
  ushort* bfAc = bfB  + (size_t)NROW*DD;
  ushort* bfBc = bfAc + (size_t)NROW*DD;
  float* xpart  = ws + (size_t)4*NROW*DD;          // 128*DD
  float* minval = xpart + 128*DD;                  // NROW*8
  int*   minidx = (int*)(minval + (size_t)NROW*8); // NROW*8

  k_front<<<dim3(128, 3), 256, 0, stream>>>(inputs, coords, cc, targets, Wc, bc, Wcc, bcc,
                                            Wa, ba, Wb, bb, W1l, W1r,
                                            bfA, bfB, bfAc, bfBc, Pg, Qg, xpart, out);
  k_adj  <<<dim3(8, 8, 4), 256, 0, stream>>>(bfA, bfB, bfAc, bfBc, minval, minidx, out);
  k_tail <<<64, 256, 0, stream>>>(Pg, Qg, xpart, W1l, b1l, minval, minidx,
                                  W2l, b2l, W2r, out);
}